// Round 5
// baseline (310.960 us; speedup 1.0000x reference)
//
#include <hip/hip_runtime.h>
#include <hip/hip_bf16.h>

// B=16384; per batch, Gram of the 27x128 fp32 matrix [dense(1x128); sparse(26x128)].
// Output row (fp32): [dense(128) | sd(26) | triu pairs(325)] = 479.
// bf16 MFMA 16x16x32, frags loaded directly global->register. ZERO __syncthreads:
// each wave is an independent streamer with a wave-private LDS stage, looping over
// GPW batches. ALL global stores are scalar dwords (row base b*479*4 is only 4B
// aligned -- R4's vector stores at that alignment silently corrupted output).
#define NBATCH 16384
#define NF 26
#define ND 128
#define OUTW 479
#define WPB 4          // waves per block
#define GPW 2          // batches per wave
#define NBLK (NBATCH / (WPB * GPW))   // 2048 blocks

typedef __attribute__((ext_vector_type(8))) __bf16 bf16x8;
typedef __attribute__((ext_vector_type(4))) float floatx4;

__device__ __forceinline__ bf16x8 cvt8(floatx4 a, floatx4 b) {
    return (bf16x8){(__bf16)a.x, (__bf16)a.y, (__bf16)a.z, (__bf16)a.w,
                    (__bf16)b.x, (__bf16)b.y, (__bf16)b.z, (__bf16)b.w};
}

__global__ __launch_bounds__(256, 4)
void interaction_kernel(const float* __restrict__ dense,
                        const float* __restrict__ sparse,
                        float* __restrict__ out)
{
    __shared__ float stage[WPB * 352];   // wave-private sd+pairs stage (1408 B/wave)

    const int t    = threadIdx.x;
    const int wave = t >> 6;
    const int lane = t & 63;
    const int quad = lane >> 4;   // 0..3
    const int lrow = lane & 15;   // 0..15

    float* sb = &stage[wave * 352];

    // f1 covers Gram rows 16..31 = sparse rows 15..26; lrow>=11 OOB -> clamp to 25
    int r1 = 15 + lrow; if (r1 > NF - 1) r1 = NF - 1;

    for (int g = 0; g < GPW; ++g) {
        const int b = (blockIdx.x * WPB + wave) * GPW + g;
        float* outrow = out + (size_t)b * OUTW;

        // ---- dense passthrough, exact fp32, scalar dwords (coalesced 256B/wave) ----
        float d0 = dense[(size_t)b * ND + lane];
        float d1 = dense[(size_t)b * ND + 64 + lane];

        // ---- fragment loads: 16 dwordx4/lane, all 16B-aligned (row bases 512B) ----
        const float* base0 = (lrow == 0)
            ? dense  + (size_t)b * ND
            : sparse + ((size_t)b * NF + (lrow - 1)) * ND;        // Gram rows 0..15
        const float* base1 = sparse + ((size_t)b * NF + r1) * ND; // Gram rows 16..31

        bf16x8 f0[4], f1[4];
        #pragma unroll
        for (int k = 0; k < 4; ++k) {
            const int off = k * 32 + quad * 8;
            floatx4 a0 = *(const floatx4*)(base0 + off);
            floatx4 a1 = *(const floatx4*)(base0 + off + 4);
            floatx4 c0 = *(const floatx4*)(base1 + off);
            floatx4 c1 = *(const floatx4*)(base1 + off + 4);
            f0[k] = cvt8(a0, a1);
            f1[k] = cvt8(c0, c1);
        }

        floatx4 c00 = {0.f, 0.f, 0.f, 0.f};
        floatx4 c01 = {0.f, 0.f, 0.f, 0.f};
        floatx4 c11 = {0.f, 0.f, 0.f, 0.f};
        #pragma unroll
        for (int k = 0; k < 4; ++k) {
            c00 = __builtin_amdgcn_mfma_f32_16x16x32_bf16(f0[k], f0[k], c00, 0, 0, 0);
            c01 = __builtin_amdgcn_mfma_f32_16x16x32_bf16(f0[k], f1[k], c01, 0, 0, 0);
            c11 = __builtin_amdgcn_mfma_f32_16x16x32_bf16(f1[k], f1[k], c11, 0, 0, 0);
        }

        outrow[lane]      = d0;   // dense out, scalar dwords
        outrow[64 + lane] = d1;

        // ---- scatter sd+pairs into wave-private LDS stage ----
        // C/D layout (16x16x32): col = lane&15, row = quad*4 + reg   [m89/m91]
        // stage index = output col - 128:  sd -> c-1 ;  pairs -> 26 + tri(r) + c-r-1
        auto scatter = [&](int r, int c, float v) {
            if (c <= NF && r < c) {
                int idx = (r == 0)
                    ? (c - 1)
                    : (NF + (((r - 1) * (52 - r)) >> 1) + c - r - 1);
                sb[idx] = v;
            }
        };
        #pragma unroll
        for (int rr = 0; rr < 4; ++rr) {
            int r = quad * 4 + rr;
            scatter(r,      lrow,      c00[rr]);   // tile (0,0)
            scatter(r,      16 + lrow, c01[rr]);   // tile (0,1)
            scatter(16 + r, 16 + lrow, c11[rr]);   // tile (1,1)
        }

        // pin LDS write->read ordering within the wave (no cross-wave sharing)
        __builtin_amdgcn_wave_barrier();
        __builtin_amdgcn_s_waitcnt(0xc07f);   // lgkmcnt(0); vmcnt/expcnt unconstrained
        __builtin_amdgcn_wave_barrier();

        // ---- read back + scalar dword stores: 351 floats, 6 strided passes ----
        #pragma unroll
        for (int j = 0; j < 6; ++j) {
            int idx = j * 64 + lane;
            if (idx < 351) outrow[128 + idx] = sb[idx];
        }
    }
}

extern "C" void kernel_launch(void* const* d_in, const int* in_sizes, int n_in,
                              void* d_out, int out_size, void* d_ws, size_t ws_size,
                              hipStream_t stream) {
    const float* dense  = (const float*)d_in[0];
    const float* sparse = (const float*)d_in[1];
    float* out = (float*)d_out;
    dim3 grid(NBLK);
    dim3 block(256);
    hipLaunchKernelGGL(interaction_kernel, grid, block, 0, stream, dense, sparse, out);
}